// Round 16
// baseline (381.240 us; speedup 1.0000x reference)
//
#include <hip/hip_runtime.h>

#define HID 128
#define NRBF 20
#define KNN 16
#define NNODE 4096
#define NBATCH 8
#define CAP 112

typedef __attribute__((ext_vector_type(8))) short short8;
typedef __attribute__((ext_vector_type(4))) float f32x4;

// branchless RNE f32->bf16 (inputs finite here)
__device__ __forceinline__ short f2bf(float x) {
  unsigned u = __builtin_bit_cast(unsigned, x);
  u = u + 0x7FFFu + ((u >> 16) & 1u);
  return (short)(u >> 16);
}
__device__ __forceinline__ float silu_f(float x) {
  return x * __builtin_amdgcn_rcpf(1.0f + __expf(-x));  // ~1e-7 rel err << bf16 rounding
}
__device__ __forceinline__ short8 cv8(const float* p) {
  f32x4 a = *(const f32x4*)p;
  f32x4 b = *(const f32x4*)(p + 4);
  short8 r;
  r[0]=f2bf(a[0]); r[1]=f2bf(a[1]); r[2]=f2bf(a[2]); r[3]=f2bf(a[3]);
  r[4]=f2bf(b[0]); r[5]=f2bf(b[1]); r[6]=f2bf(b[2]); r[7]=f2bf(b[3]);
  return r;
}

// ---------------------------------------------------------------------------
// Kernel W: stage ew1/ew2 -> bf16 fragment-linear weight buffers in ws (once).
// Same layout math as the R12 LDS staging. 106 KB total, L2-resident after.
// ---------------------------------------------------------------------------
__global__ __launch_bounds__(256)
void wprep_kernel(const float* __restrict__ ew1, const float* __restrict__ ew2,
                  short8* __restrict__ wb1, short8* __restrict__ wb2)
{
  int f = blockIdx.x * 256 + threadIdx.x;
  if (f < 9*8*64) {
    int kc = f >> 9, rem = f & 511, nf = rem >> 6, ln = rem & 63;
    int kb = kc*32 + (ln >> 4)*8, col = nf*16 + (ln & 15);
    short8 v;
    #pragma unroll
    for (int e = 0; e < 8; ++e) {
      int k = kb + e;
      v[e] = (k < 276) ? f2bf(ew1[k*128 + col]) : (short)0;
    }
    wb1[f] = v;
  } else if (f < 9*8*64 + 4*8*64) {
    int g = f - 9*8*64;
    int kc = g >> 9, rem = g & 511, nf = rem >> 6, ln = rem & 63;
    int kb = kc*32 + (ln >> 4)*8, col = nf*16 + (ln & 15);
    short8 v;
    #pragma unroll
    for (int e = 0; e < 8; ++e) v[e] = f2bf(ew2[(kb + e)*128 + col]);
    wb2[g] = v;
  }
}

// ---------------------------------------------------------------------------
// Kernel 0: h (f32) -> hb (bf16), once. BW-bound (~3-5 us).
// ---------------------------------------------------------------------------
__global__ __launch_bounds__(256)
void hcvt_kernel(const float* __restrict__ h, short* __restrict__ hb)
{
  size_t i = ((size_t)blockIdx.x * 256 + threadIdx.x) * 8;
  *(short8*)(hb + i) = cv8(h + i);
}

// ---------------------------------------------------------------------------
// Kernel 1: exact kNN (unchanged R14). FMA fast-scan + inflated threshold;
// exact d2 recomputed for <=CAP candidates; exact stable rank selection.
// ---------------------------------------------------------------------------
__global__ __launch_bounds__(512)
void knn_kernel(const float* __restrict__ pos,
                int* __restrict__ eidx, float* __restrict__ edist)
{
  __shared__ float pX[NNODE], pY[NNODE], pZ[NNODE];   // 48 KB
  __shared__ float d2b[8][4][CAP];                    // 14 KB
  __shared__ int   jb[8][4][CAP];                     // 14 KB
  __shared__ int   cntL[8][4];

  const int tid  = threadIdx.x;
  const int wv   = tid >> 6;
  const int lane = tid & 63;
  const int b    = blockIdx.x >> 7;
  const int grp  = blockIdx.x & 127;

  const float* pb = pos + (size_t)b * NNODE * 3;
  for (int idx = tid; idx < NNODE; idx += 512) {
    pX[idx] = pb[idx*3]; pY[idx] = pb[idx*3+1]; pZ[idx] = pb[idx*3+2];
  }
  __syncthreads();

  const int i0 = grp * 32 + wv * 4;
  float pix[4], piy[4], piz[4];
  #pragma unroll
  for (int n = 0; n < 4; ++n) { pix[n]=pX[i0+n]; piy[n]=pY[i0+n]; piz[n]=pZ[i0+n]; }

  float vmin0[4] = {3.0e38f, 3.0e38f, 3.0e38f, 3.0e38f};
  float vmin1[4] = {3.0e38f, 3.0e38f, 3.0e38f, 3.0e38f};
  #pragma unroll 4
  for (int t = 0; t < 64; t += 2) {
    const int j0 = t*64 + lane, j1 = j0 + 64;
    const float x0 = pX[j0], y0 = pY[j0], z0 = pZ[j0];
    const float x1 = pX[j1], y1 = pY[j1], z1 = pZ[j1];
    #pragma unroll
    for (int n = 0; n < 4; ++n) {
      float dx0 = pix[n]-x0, dy0 = piy[n]-y0, dz0 = piz[n]-z0;
      vmin0[n] = fminf(vmin0[n], fmaf(dz0,dz0, fmaf(dy0,dy0, dx0*dx0)));
      float dx1 = pix[n]-x1, dy1 = piy[n]-y1, dz1 = piz[n]-z1;
      vmin1[n] = fminf(vmin1[n], fmaf(dz1,dz1, fmaf(dy1,dy1, dx1*dx1)));
    }
  }

  float Tp[4];
  #pragma unroll
  for (int n = 0; n < 4; ++n) {
    float v = fminf(vmin0[n], vmin1[n]);
    #pragma unroll
    for (int k = 2; k <= 64; k <<= 1) {
      #pragma unroll
      for (int jj = k >> 1; jj > 0; jj >>= 1) {
        float o = __shfl_xor(v, jj);
        const bool up   = ((lane & k) == 0);
        const bool lowl = ((lane & jj) == 0);
        float mn = fminf(v, o), mx = fmaxf(v, o);
        v = (up == lowl) ? mn : mx;
      }
    }
    float Tf = __shfl(v, 16);
    Tp[n] = Tf * (1.0f + 2.0e-6f) + 1.0e-35f;
  }

  if (lane < 4) cntL[wv][lane] = 0;
  #pragma unroll 2
  for (int t = 0; t < 64; ++t) {
    const int j = t * 64 + lane;
    const float x = pX[j], y = pY[j], z = pZ[j];
    #pragma unroll
    for (int n = 0; n < 4; ++n) {
      float dx = pix[n] - x, dy = piy[n] - y, dz = piz[n] - z;
      float d2 = fmaf(dz, dz, fmaf(dy, dy, dx * dx));
      if ((j != i0 + n) && (d2 <= Tp[n])) {
        int p = atomicAdd(&cntL[wv][n], 1);
        if (p < CAP) jb[wv][n][p] = j;
      }
    }
  }

  #pragma unroll 1
  for (int n = 0; n < 4; ++n) {
    int cnt = cntL[wv][n];
    if (cnt > CAP) cnt = CAP;
    for (int s = lane; s < cnt; s += 64) {
      int j = jb[wv][n][s];
      float dx = __fsub_rn(pix[n], pX[j]);
      float dy = __fsub_rn(piy[n], pY[j]);
      float dz = __fsub_rn(piz[n], pZ[j]);
      d2b[wv][n][s] = __fadd_rn(__fadd_rn(__fmul_rn(dx,dx), __fmul_rn(dy,dy)),
                                __fmul_rn(dz,dz));
    }
    for (int s = lane; s < cnt; s += 64) {
      float dm = d2b[wv][n][s]; int jm = jb[wv][n][s];
      int rank = 0;
      for (int c = 0; c < cnt; ++c) {
        float dc = d2b[wv][n][c]; int jc = jb[wv][n][c];
        if (dc < dm || (dc == dm && jc < jm)) ++rank;
      }
      if (rank < KNN) {
        size_t base = ((size_t)b * NNODE + i0 + n) * KNN;
        eidx[base + rank]  = b * NNODE + jm;
        edist[base + rank] = sqrtf(__fadd_rn(dm, 1e-8f));
      }
    }
  }
}

// ---------------------------------------------------------------------------
// Kernel 2: fused edge MLP + mask + aggregate — R12's verified arithmetic,
// but F1 B-fragments read from GLOBAL wb1 (L2-hot) instead of LDS.
// LDS = F2 (32 KB) + m1s (32 KB) = 65.5 KB -> 2 blocks/CU = 4 waves/SIMD
// (VGPR ~116 <= 128, so 16 waves/CU fit the register file).
// ---------------------------------------------------------------------------
#define ENPW 8

template<bool HBF>
__global__ __launch_bounds__(512)
void edge_kernel(const float* __restrict__ h, const short* __restrict__ hb,
                 const int* __restrict__ eidx, const float* __restrict__ edist,
                 const short8* __restrict__ wb1, const short8* __restrict__ wb2,
                 const float* __restrict__ eb1, const float* __restrict__ eb2,
                 float* __restrict__ agg)
{
  __shared__ __attribute__((aligned(16))) short8 F2[4*8*64];   // 32,768 B
  __shared__ __attribute__((aligned(16))) short m1s[8][2048];  // 32,768 B

  const int tid = threadIdx.x;
  for (int f = tid; f < 4*8*64; f += 512) F2[f] = wb2[f];
  __syncthreads();

  const int wv = tid >> 6, lane = tid & 63;
  const int lo = lane & 15, hi = lane >> 4;
  short* m1w = &m1s[wv][0];

  float b1v[8], b2v[8];
  #pragma unroll
  for (int nf = 0; nf < 8; ++nf) {
    b1v[nf] = eb1[nf*16 + lo];
    b2v[nf] = eb2[nf*16 + lo];
  }
  int wbase[4], xmask[4], rbase[4];
  #pragma unroll
  for (int q = 0; q < 4; ++q) {
    int row = hi*4 + q;
    wbase[q] = (row << 8) + (lo << 1);
    xmask[q] = (row & 7) << 4;
  }
  #pragma unroll
  for (int kc = 0; kc < 4; ++kc)
    rbase[kc] = ((lo << 8) + ((kc*32 + hi*8) << 1)) ^ ((lo & 7) << 4);

  const f32x4 zero4 = {0.f, 0.f, 0.f, 0.f};
  const int nbase = (blockIdx.x * 8 + wv) * ENPW;

  #pragma unroll 1
  for (int it = 0; it < ENPW/2; ++it) {
    const int nA = nbase + it*2, nB = nA + 1;
    int jgA = eidx[(size_t)nA*KNN + lo] & (NBATCH*NNODE - 1);
    int jgB = eidx[(size_t)nB*KNN + lo] & (NBATCH*NNODE - 1);
    const float deA = edist[(size_t)nA*KNN + lo];
    const float deB = edist[(size_t)nB*KNN + lo];

    short8 aIA[4], aJA[4], aIB[4], aJB[4];
    #pragma unroll
    for (int kc = 0; kc < 4; ++kc) {
      if constexpr (HBF) {
        aIA[kc] = *(const short8*)(hb + (size_t)nA*HID  + kc*32 + hi*8);
        aJA[kc] = *(const short8*)(hb + (size_t)jgA*HID + kc*32 + hi*8);
        aIB[kc] = *(const short8*)(hb + (size_t)nB*HID  + kc*32 + hi*8);
        aJB[kc] = *(const short8*)(hb + (size_t)jgB*HID + kc*32 + hi*8);
      } else {
        aIA[kc] = cv8(h + (size_t)nA*HID  + kc*32 + hi*8);
        aJA[kc] = cv8(h + (size_t)jgA*HID + kc*32 + hi*8);
        aIB[kc] = cv8(h + (size_t)nB*HID  + kc*32 + hi*8);
        aJB[kc] = cv8(h + (size_t)jgB*HID + kc*32 + hi*8);
      }
    }
    short8 aRA, aRB;
    #pragma unroll
    for (int e = 0; e < 8; ++e) {
      const int r = hi*8 + e;
      float vA = 0.f, vB = 0.f;
      if (r < NRBF) {
        const float cr = (float)(r * (5.0/19.0));
        float tA = __fsub_rn(deA, cr), tB = __fsub_rn(deB, cr);
        vA = __expf(-16.0f * __fmul_rn(tA, tA));
        vB = __expf(-16.0f * __fmul_rn(tB, tB));
      }
      aRA[e] = f2bf(vA); aRB[e] = f2bf(vB);
    }

    f32x4 acc1A[8], acc1B[8];
    #pragma unroll
    for (int nf = 0; nf < 8; ++nf) { acc1A[nf] = zero4; acc1B[nf] = zero4; }
    __builtin_amdgcn_s_setprio(1);
    #pragma unroll
    for (int kc = 0; kc < 9; ++kc) {
      short8 aA = (kc < 4) ? aIA[kc] : ((kc < 8) ? aJA[kc-4] : aRA);
      short8 aB = (kc < 4) ? aIB[kc] : ((kc < 8) ? aJB[kc-4] : aRB);
      #pragma unroll
      for (int nf = 0; nf < 8; ++nf) {
        short8 bfv = wb1[(kc*8 + nf)*64 + lane];   // GLOBAL, L2-hot, coalesced
        acc1A[nf] = __builtin_amdgcn_mfma_f32_16x16x32_bf16(aA, bfv, acc1A[nf], 0,0,0);
        acc1B[nf] = __builtin_amdgcn_mfma_f32_16x16x32_bf16(aB, bfv, acc1B[nf], 0,0,0);
      }
    }
    __builtin_amdgcn_s_setprio(0);

    // m1 transpose through ONE per-wave LDS buffer (same-wave DS ordering)
    short8 a2A[4], a2B[4];
    #pragma unroll
    for (int nf = 0; nf < 8; ++nf) {
      #pragma unroll
      for (int q = 0; q < 4; ++q) {
        int off = (wbase[q] + (nf << 5)) ^ xmask[q];
        *(short*)((char*)m1w + off) = f2bf(silu_f(acc1A[nf][q] + b1v[nf]));
      }
    }
    #pragma unroll
    for (int kc = 0; kc < 4; ++kc)
      a2A[kc] = *(const short8*)((char*)m1w + rbase[kc]);
    #pragma unroll
    for (int nf = 0; nf < 8; ++nf) {
      #pragma unroll
      for (int q = 0; q < 4; ++q) {
        int off = (wbase[q] + (nf << 5)) ^ xmask[q];
        *(short*)((char*)m1w + off) = f2bf(silu_f(acc1B[nf][q] + b1v[nf]));
      }
    }
    #pragma unroll
    for (int kc = 0; kc < 4; ++kc)
      a2B[kc] = *(const short8*)((char*)m1w + rbase[kc]);

    f32x4 acc2A[8], acc2B[8];
    #pragma unroll
    for (int nf = 0; nf < 8; ++nf) { acc2A[nf] = zero4; acc2B[nf] = zero4; }
    __builtin_amdgcn_s_setprio(1);
    #pragma unroll
    for (int kc = 0; kc < 4; ++kc) {
      #pragma unroll
      for (int nf = 0; nf < 8; ++nf) {
        short8 bfv = F2[(kc*8 + nf)*64 + lane];
        acc2A[nf] = __builtin_amdgcn_mfma_f32_16x16x32_bf16(a2A[kc], bfv, acc2A[nf], 0,0,0);
        acc2B[nf] = __builtin_amdgcn_mfma_f32_16x16x32_bf16(a2B[kc], bfv, acc2B[nf], 0,0,0);
      }
    }
    __builtin_amdgcn_s_setprio(0);

    float dqA[4], dqB[4];
    #pragma unroll
    for (int q = 0; q < 4; ++q) {
      dqA[q] = __shfl(deA, hi*4 + q);
      dqB[q] = __shfl(deB, hi*4 + q);
    }
    #pragma unroll
    for (int nf = 0; nf < 8; ++nf) {
      float sA = 0.f, sB = 0.f;
      #pragma unroll
      for (int q = 0; q < 4; ++q) {
        float mA = silu_f(acc2A[nf][q] + b2v[nf]);
        float mB = silu_f(acc2B[nf][q] + b2v[nf]);
        sA += (dqA[q] < 5.0f) ? mA : 0.f;
        sB += (dqB[q] < 5.0f) ? mB : 0.f;
      }
      sA += __shfl_xor(sA, 16); sA += __shfl_xor(sA, 32);
      sB += __shfl_xor(sB, 16); sB += __shfl_xor(sB, 32);
      if (hi == 0) {
        agg[(size_t)nA*HID + nf*16 + lo] = sA;
        agg[(size_t)nB*HID + nf*16 + lo] = sB;
      }
    }
  }
}

// ---------------------------------------------------------------------------
// Kernel 3: node MLP + residual + LayerNorm, agg==out in-place. (unchanged)
// ---------------------------------------------------------------------------
template<bool HBF>
__global__ __launch_bounds__(512)
void node_kernel(const float* __restrict__ h, const short* __restrict__ hb,
                 const float* agg,
                 const float* __restrict__ nw1, const float* __restrict__ nb1,
                 const float* __restrict__ nw2, const float* __restrict__ nb2,
                 const float* __restrict__ gam, const float* __restrict__ bet,
                 float* out)
{
  __shared__ __attribute__((aligned(16))) short8 G1[8*8*64];
  __shared__ __attribute__((aligned(16))) short8 G2[4*8*64];
  __shared__ __attribute__((aligned(16))) short m1s[8][2048];

  const int tid = threadIdx.x;
  for (int f = tid; f < 8*8*64; f += 512) {
    int kc = f >> 9, rem = f & 511, nf = rem >> 6, ln = rem & 63;
    int kb = kc*32 + (ln >> 4)*8, col = nf*16 + (ln & 15);
    short8 v;
    #pragma unroll
    for (int e = 0; e < 8; ++e) v[e] = f2bf(nw1[(kb + e)*128 + col]);
    G1[f] = v;
  }
  for (int f = tid; f < 4*8*64; f += 512) {
    int kc = f >> 9, rem = f & 511, nf = rem >> 6, ln = rem & 63;
    int kb = kc*32 + (ln >> 4)*8, col = nf*16 + (ln & 15);
    short8 v;
    #pragma unroll
    for (int e = 0; e < 8; ++e) v[e] = f2bf(nw2[(kb + e)*128 + col]);
    G2[f] = v;
  }
  __syncthreads();

  const int wv = tid >> 6, lane = tid & 63;
  const int lo = lane & 15, hi = lane >> 4;
  short* m1w = &m1s[wv][0];

  float b1v[8], b2v[8], gv[8], bv[8];
  #pragma unroll
  for (int nf = 0; nf < 8; ++nf) {
    b1v[nf] = nb1[nf*16 + lo];
    b2v[nf] = nb2[nf*16 + lo];
    gv[nf]  = gam[nf*16 + lo];
    bv[nf]  = bet[nf*16 + lo];
  }
  const f32x4 zero4 = {0.f, 0.f, 0.f, 0.f};

  const int row0 = (blockIdx.x * 8 + wv) * 16;

  const float* hrow = h   + (size_t)(row0 + lo) * HID;
  const float* arow = agg + (size_t)(row0 + lo) * HID;
  const short* hbrow = hb + (size_t)(row0 + lo) * HID;

  f32x4 acc1[8];
  #pragma unroll
  for (int nf = 0; nf < 8; ++nf) acc1[nf] = zero4;
  #pragma unroll
  for (int kc = 0; kc < 8; ++kc) {
    short8 a;
    if (kc < 4) {
      if constexpr (HBF) a = *(const short8*)(hbrow + kc*32 + hi*8);
      else               a = cv8(hrow + kc*32 + hi*8);
    } else {
      a = cv8(arow + (kc - 4)*32 + hi*8);
    }
    #pragma unroll
    for (int nf = 0; nf < 8; ++nf) {
      short8 bfv = G1[(kc*8 + nf)*64 + lane];
      acc1[nf] = __builtin_amdgcn_mfma_f32_16x16x32_bf16(a, bfv, acc1[nf], 0,0,0);
    }
  }

  #pragma unroll
  for (int nf = 0; nf < 8; ++nf) {
    #pragma unroll
    for (int q = 0; q < 4; ++q) {
      float s = silu_f(acc1[nf][q] + b1v[nf]);
      int row = hi*4 + q, col = nf*16 + lo;
      int byteoff = ((row << 8) + (col << 1)) ^ ((row & 7) << 4);
      *(short*)((char*)m1w + byteoff) = f2bf(s);
    }
  }

  f32x4 acc2[8];
  #pragma unroll
  for (int nf = 0; nf < 8; ++nf) acc2[nf] = zero4;
  #pragma unroll
  for (int kc = 0; kc < 4; ++kc) {
    int byteA = ((lo << 8) + ((kc*32 + hi*8) << 1)) ^ ((lo & 7) << 4);
    short8 a = *(const short8*)((char*)m1w + byteA);
    #pragma unroll
    for (int nf = 0; nf < 8; ++nf) {
      short8 bfv = G2[(kc*8 + nf)*64 + lane];
      acc2[nf] = __builtin_amdgcn_mfma_f32_16x16x32_bf16(a, bfv, acc2[nf], 0,0,0);
    }
  }

  float xv[4][8];
  #pragma unroll
  for (int nf = 0; nf < 8; ++nf) {
    #pragma unroll
    for (int q = 0; q < 4; ++q) {
      xv[q][nf] = acc2[nf][q] + b2v[nf]
                + h[(size_t)(row0 + hi*4 + q) * HID + nf*16 + lo];
    }
  }

  #pragma unroll
  for (int q = 0; q < 4; ++q) {
    float s = 0.0f;
    #pragma unroll
    for (int nf = 0; nf < 8; ++nf) s += xv[q][nf];
    s += __shfl_xor(s, 1); s += __shfl_xor(s, 2);
    s += __shfl_xor(s, 4); s += __shfl_xor(s, 8);
    float mu = s * 0.0078125f;
    float t = 0.0f;
    #pragma unroll
    for (int nf = 0; nf < 8; ++nf) { float d = xv[q][nf] - mu; t += d * d; }
    t += __shfl_xor(t, 1); t += __shfl_xor(t, 2);
    t += __shfl_xor(t, 4); t += __shfl_xor(t, 8);
    float inv = 1.0f / sqrtf(t * 0.0078125f + 1e-5f);
    #pragma unroll
    for (int nf = 0; nf < 8; ++nf) {
      float y = (xv[q][nf] - mu) * inv * gv[nf] + bv[nf];
      out[(size_t)(row0 + hi*4 + q) * HID + nf*16 + lo] = y;
    }
  }
}

// ---------------------------------------------------------------------------
extern "C" void kernel_launch(void* const* d_in, const int* in_sizes, int n_in,
                              void* d_out, int out_size, void* d_ws, size_t ws_size,
                              hipStream_t stream) {
  (void)in_sizes; (void)n_in; (void)out_size;
  const float* h   = (const float*)d_in[0];
  const float* pos = (const float*)d_in[1];
  const float* ew1 = (const float*)d_in[2];
  const float* eb1 = (const float*)d_in[3];
  const float* ew2 = (const float*)d_in[4];
  const float* eb2 = (const float*)d_in[5];
  const float* nw1 = (const float*)d_in[6];
  const float* nb1 = (const float*)d_in[7];
  const float* nw2 = (const float*)d_in[8];
  const float* nb2 = (const float*)d_in[9];
  const float* gam = (const float*)d_in[10];
  const float* bet = (const float*)d_in[11];

  // ws: eidx 2MB | edist 2MB | wb1 73.7KB | wb2 32.8KB | hb 8.4MB (optional)
  const size_t sz_ed  = (size_t)NBATCH * NNODE * KNN * 8;          // 4 MB
  const size_t sz_wb1 = (size_t)(9*8*64) * 16;                     // 73,728 B
  const size_t sz_wb2 = (size_t)(4*8*64) * 16;                     // 32,768 B
  const size_t sz_hb  = (size_t)NBATCH * NNODE * HID * 2;          // 8.4 MB
  const size_t need   = sz_ed + sz_wb1 + sz_wb2;
  if (ws_size < need) return;
  const bool use_hbf = (ws_size >= need + sz_hb);

  char* wsp = (char*)d_ws;
  int*    eidx  = (int*)wsp;
  float*  edist = (float*)(wsp + sz_ed / 2);
  short8* wb1   = (short8*)(wsp + sz_ed);
  short8* wb2   = (short8*)(wsp + sz_ed + sz_wb1);
  short*  hb    = (short*)(wsp + need);
  float*  agg   = (float*)d_out;

  wprep_kernel<<<dim3(26), dim3(256), 0, stream>>>(ew1, ew2, wb1, wb2);
  if (use_hbf) {
    hcvt_kernel<<<dim3(2048), dim3(256), 0, stream>>>(h, hb);
  }
  knn_kernel<<<dim3(1024), dim3(512), 0, stream>>>(pos, eidx, edist);
  if (use_hbf) {
    edge_kernel<true ><<<dim3(512), dim3(512), 0, stream>>>(h, hb, eidx, edist,
                                                            wb1, wb2, eb1, eb2, agg);
    node_kernel<true ><<<dim3(256), dim3(512), 0, stream>>>(h, hb, agg, nw1, nb1,
                                                            nw2, nb2, gam, bet, (float*)d_out);
  } else {
    edge_kernel<false><<<dim3(512), dim3(512), 0, stream>>>(h, hb, eidx, edist,
                                                            wb1, wb2, eb1, eb2, agg);
    node_kernel<false><<<dim3(256), dim3(512), 0, stream>>>(h, hb, agg, nw1, nb1,
                                                            nw2, nb2, gam, bet, (float*)d_out);
  }
}

// Round 17
// 204.106 us; speedup vs baseline: 1.8679x; 1.8679x over previous
//
#include <hip/hip_runtime.h>

#define HID 128
#define NRBF 20
#define KNN 16
#define NNODE 4096
#define NBATCH 8
#define CAP 112

typedef __attribute__((ext_vector_type(8))) short short8;
typedef __attribute__((ext_vector_type(4))) float f32x4;

// branchless RNE f32->bf16 (inputs finite here)
__device__ __forceinline__ short f2bf(float x) {
  unsigned u = __builtin_bit_cast(unsigned, x);
  u = u + 0x7FFFu + ((u >> 16) & 1u);
  return (short)(u >> 16);
}
__device__ __forceinline__ float silu_f(float x) {
  return x * __builtin_amdgcn_rcpf(1.0f + __expf(-x));  // ~1e-7 rel err << bf16 rounding
}
__device__ __forceinline__ short8 cv8(const float* p) {
  f32x4 a = *(const f32x4*)p;
  f32x4 b = *(const f32x4*)(p + 4);
  short8 r;
  r[0]=f2bf(a[0]); r[1]=f2bf(a[1]); r[2]=f2bf(a[2]); r[3]=f2bf(a[3]);
  r[4]=f2bf(b[0]); r[5]=f2bf(b[1]); r[6]=f2bf(b[2]); r[7]=f2bf(b[3]);
  return r;
}

// ---------------------------------------------------------------------------
// Kernel 0: h (f32) -> hb (bf16), once. BW-bound (~3-5 us).
// ---------------------------------------------------------------------------
__global__ __launch_bounds__(256)
void hcvt_kernel(const float* __restrict__ h, short* __restrict__ hb)
{
  size_t i = ((size_t)blockIdx.x * 256 + threadIdx.x) * 8;
  *(short8*)(hb + i) = cv8(h + i);
}

// ---------------------------------------------------------------------------
// Kernel 1: exact kNN (proven R13/R14 form). FMA fast-scan + inflated
// threshold; exact d2 recomputed for <=CAP candidates; exact stable rank.
// ---------------------------------------------------------------------------
__global__ __launch_bounds__(512)
void knn_kernel(const float* __restrict__ pos,
                int* __restrict__ eidx, float* __restrict__ edist)
{
  __shared__ float pX[NNODE], pY[NNODE], pZ[NNODE];   // 48 KB
  __shared__ float d2b[8][4][CAP];                    // 14 KB
  __shared__ int   jb[8][4][CAP];                     // 14 KB
  __shared__ int   cntL[8][4];

  const int tid  = threadIdx.x;
  const int wv   = tid >> 6;
  const int lane = tid & 63;
  const int b    = blockIdx.x >> 7;
  const int grp  = blockIdx.x & 127;

  const float* pb = pos + (size_t)b * NNODE * 3;
  for (int idx = tid; idx < NNODE; idx += 512) {
    pX[idx] = pb[idx*3]; pY[idx] = pb[idx*3+1]; pZ[idx] = pb[idx*3+2];
  }
  __syncthreads();

  const int i0 = grp * 32 + wv * 4;
  float pix[4], piy[4], piz[4];
  #pragma unroll
  for (int n = 0; n < 4; ++n) { pix[n]=pX[i0+n]; piy[n]=pY[i0+n]; piz[n]=pZ[i0+n]; }

  // pass 1: per-lane strip minima of FAST d2, 2 chains (self included, =0)
  float vmin0[4] = {3.0e38f, 3.0e38f, 3.0e38f, 3.0e38f};
  float vmin1[4] = {3.0e38f, 3.0e38f, 3.0e38f, 3.0e38f};
  #pragma unroll 4
  for (int t = 0; t < 64; t += 2) {
    const int j0 = t*64 + lane, j1 = j0 + 64;
    const float x0 = pX[j0], y0 = pY[j0], z0 = pZ[j0];
    const float x1 = pX[j1], y1 = pY[j1], z1 = pZ[j1];
    #pragma unroll
    for (int n = 0; n < 4; ++n) {
      float dx0 = pix[n]-x0, dy0 = piy[n]-y0, dz0 = piz[n]-z0;
      vmin0[n] = fminf(vmin0[n], fmaf(dz0,dz0, fmaf(dy0,dy0, dx0*dx0)));
      float dx1 = pix[n]-x1, dy1 = piy[n]-y1, dz1 = piz[n]-z1;
      vmin1[n] = fminf(vmin1[n], fmaf(dz1,dz1, fmaf(dy1,dy1, dx1*dx1)));
    }
  }

  float Tp[4];
  #pragma unroll
  for (int n = 0; n < 4; ++n) {
    float v = fminf(vmin0[n], vmin1[n]);   // exact min merge
    #pragma unroll
    for (int k = 2; k <= 64; k <<= 1) {
      #pragma unroll
      for (int jj = k >> 1; jj > 0; jj >>= 1) {
        float o = __shfl_xor(v, jj);
        const bool up   = ((lane & k) == 0);
        const bool lowl = ((lane & jj) == 0);
        float mn = fminf(v, o), mx = fmaxf(v, o);
        v = (up == lowl) ? mn : mx;
      }
    }
    float Tf = __shfl(v, 16);          // elem 16: >= 16th non-self FAST dist
    Tp[n] = Tf * (1.0f + 2.0e-6f) + 1.0e-35f;  // covers fast<->exact skew
  }

  if (lane < 4) cntL[wv][lane] = 0;
  // pass 2: ONE batched FAST scan, compact indices only
  #pragma unroll 2
  for (int t = 0; t < 64; ++t) {
    const int j = t * 64 + lane;
    const float x = pX[j], y = pY[j], z = pZ[j];
    #pragma unroll
    for (int n = 0; n < 4; ++n) {
      float dx = pix[n] - x, dy = piy[n] - y, dz = piz[n] - z;
      float d2 = fmaf(dz, dz, fmaf(dy, dy, dx * dx));
      if ((j != i0 + n) && (d2 <= Tp[n])) {
        int p = atomicAdd(&cntL[wv][n], 1);
        if (p < CAP) jb[wv][n][p] = j;
      }
    }
  }

  // recompute EXACT d2 for compacted candidates, then exact stable selection
  #pragma unroll 1
  for (int n = 0; n < 4; ++n) {
    int cnt = cntL[wv][n];
    if (cnt > CAP) cnt = CAP;
    for (int s = lane; s < cnt; s += 64) {
      int j = jb[wv][n][s];
      float dx = __fsub_rn(pix[n], pX[j]);
      float dy = __fsub_rn(piy[n], pY[j]);
      float dz = __fsub_rn(piz[n], pZ[j]);
      d2b[wv][n][s] = __fadd_rn(__fadd_rn(__fmul_rn(dx,dx), __fmul_rn(dy,dy)),
                                __fmul_rn(dz,dz));
    }
    for (int s = lane; s < cnt; s += 64) {
      float dm = d2b[wv][n][s]; int jm = jb[wv][n][s];
      int rank = 0;
      for (int c = 0; c < cnt; ++c) {
        float dc = d2b[wv][n][c]; int jc = jb[wv][n][c];
        if (dc < dm || (dc == dm && jc < jm)) ++rank;
      }
      if (rank < KNN) {
        size_t base = ((size_t)b * NNODE + i0 + n) * KNN;
        eidx[base + rank]  = b * NNODE + jm;
        edist[base + rank] = sqrtf(__fadd_rn(dm, 1e-8f));
      }
    }
  }
}

// ---------------------------------------------------------------------------
// Kernel 2: edge MLP + mask + aggregate — R12's PROVEN shape (512-thr,
// VGPR ~116, no spills) + XCD-AWARE block swizzle: block i runs on XCD i%8;
// remap i -> chunk (i%8)*32 + i/8 so each XCD's 32 blocks cover exactly one
// batch (hb slice 1 MB) -> gathers become L2-hits after compulsory fills.
// Bijective for grid=256 (256%8==0).
// ---------------------------------------------------------------------------
#define ENPW 16

template<bool HBF>
__global__ __launch_bounds__(512)
void edge_kernel(const float* __restrict__ h, const short* __restrict__ hb,
                 const int* __restrict__ eidx, const float* __restrict__ edist,
                 const float* __restrict__ ew1, const float* __restrict__ eb1,
                 const float* __restrict__ ew2, const float* __restrict__ eb2,
                 float* __restrict__ agg)
{
  __shared__ __attribute__((aligned(16))) short8 F1[9*8*64];   // 73,728 B
  __shared__ __attribute__((aligned(16))) short8 F2[4*8*64];   // 32,768 B
  __shared__ __attribute__((aligned(16))) short m1s[8][2048];  // 32,768 B

  const int tid = threadIdx.x;
  for (int f = tid; f < 9*8*64; f += 512) {
    int kc = f >> 9, rem = f & 511, nf = rem >> 6, ln = rem & 63;
    int kb = kc*32 + (ln >> 4)*8, col = nf*16 + (ln & 15);
    short8 v;
    #pragma unroll
    for (int e = 0; e < 8; ++e) {
      int k = kb + e;
      v[e] = (k < 276) ? f2bf(ew1[k*128 + col]) : (short)0;
    }
    F1[f] = v;
  }
  for (int f = tid; f < 4*8*64; f += 512) {
    int kc = f >> 9, rem = f & 511, nf = rem >> 6, ln = rem & 63;
    int kb = kc*32 + (ln >> 4)*8, col = nf*16 + (ln & 15);
    short8 v;
    #pragma unroll
    for (int e = 0; e < 8; ++e) v[e] = f2bf(ew2[(kb + e)*128 + col]);
    F2[f] = v;
  }
  __syncthreads();

  const int wv = tid >> 6, lane = tid & 63;
  const int lo = lane & 15, hi = lane >> 4;
  short* m1w = &m1s[wv][0];

  float b1v[8], b2v[8];
  #pragma unroll
  for (int nf = 0; nf < 8; ++nf) {
    b1v[nf] = eb1[nf*16 + lo];
    b2v[nf] = eb2[nf*16 + lo];
  }
  int wbase[4], xmask[4], rbase[4];
  #pragma unroll
  for (int q = 0; q < 4; ++q) {
    int row = hi*4 + q;
    wbase[q] = (row << 8) + (lo << 1);
    xmask[q] = (row & 7) << 4;
  }
  #pragma unroll
  for (int kc = 0; kc < 4; ++kc)
    rbase[kc] = ((lo << 8) + ((kc*32 + hi*8) << 1)) ^ ((lo & 7) << 4);

  const f32x4 zero4 = {0.f, 0.f, 0.f, 0.f};
  // XCD swizzle: dispatch i -> XCD i%8; give XCD k the contiguous chunk k*32..
  const int swz = (blockIdx.x & 7) * 32 + (blockIdx.x >> 3);
  const int nbase = (swz * 8 + wv) * ENPW;

  #pragma unroll 1
  for (int it = 0; it < ENPW/2; ++it) {
    const int nA = nbase + it*2, nB = nA + 1;
    int jgA = eidx[(size_t)nA*KNN + lo] & (NBATCH*NNODE - 1);
    int jgB = eidx[(size_t)nB*KNN + lo] & (NBATCH*NNODE - 1);
    const float deA = edist[(size_t)nA*KNN + lo];
    const float deB = edist[(size_t)nB*KNN + lo];

    short8 aIA[4], aJA[4], aIB[4], aJB[4];
    #pragma unroll
    for (int kc = 0; kc < 4; ++kc) {
      if constexpr (HBF) {
        aIA[kc] = *(const short8*)(hb + (size_t)nA*HID  + kc*32 + hi*8);
        aJA[kc] = *(const short8*)(hb + (size_t)jgA*HID + kc*32 + hi*8);
        aIB[kc] = *(const short8*)(hb + (size_t)nB*HID  + kc*32 + hi*8);
        aJB[kc] = *(const short8*)(hb + (size_t)jgB*HID + kc*32 + hi*8);
      } else {
        aIA[kc] = cv8(h + (size_t)nA*HID  + kc*32 + hi*8);
        aJA[kc] = cv8(h + (size_t)jgA*HID + kc*32 + hi*8);
        aIB[kc] = cv8(h + (size_t)nB*HID  + kc*32 + hi*8);
        aJB[kc] = cv8(h + (size_t)jgB*HID + kc*32 + hi*8);
      }
    }
    short8 aRA, aRB;
    #pragma unroll
    for (int e = 0; e < 8; ++e) {
      const int r = hi*8 + e;
      float vA = 0.f, vB = 0.f;
      if (r < NRBF) {
        const float cr = (float)(r * (5.0/19.0));
        float tA = __fsub_rn(deA, cr), tB = __fsub_rn(deB, cr);
        vA = __expf(-16.0f * __fmul_rn(tA, tA));
        vB = __expf(-16.0f * __fmul_rn(tB, tB));
      }
      aRA[e] = f2bf(vA); aRB[e] = f2bf(vB);
    }

    f32x4 acc1A[8], acc1B[8];
    #pragma unroll
    for (int nf = 0; nf < 8; ++nf) { acc1A[nf] = zero4; acc1B[nf] = zero4; }
    __builtin_amdgcn_s_setprio(1);
    #pragma unroll
    for (int kc = 0; kc < 9; ++kc) {
      short8 aA = (kc < 4) ? aIA[kc] : ((kc < 8) ? aJA[kc-4] : aRA);
      short8 aB = (kc < 4) ? aIB[kc] : ((kc < 8) ? aJB[kc-4] : aRB);
      #pragma unroll
      for (int nf = 0; nf < 8; ++nf) {
        short8 bfv = F1[(kc*8 + nf)*64 + lane];     // one read feeds 2 MFMAs
        acc1A[nf] = __builtin_amdgcn_mfma_f32_16x16x32_bf16(aA, bfv, acc1A[nf], 0,0,0);
        acc1B[nf] = __builtin_amdgcn_mfma_f32_16x16x32_bf16(aB, bfv, acc1B[nf], 0,0,0);
      }
    }
    __builtin_amdgcn_s_setprio(0);

    // m1 transpose through ONE per-wave buffer (same-wave DS ordering)
    short8 a2A[4], a2B[4];
    #pragma unroll
    for (int nf = 0; nf < 8; ++nf) {
      #pragma unroll
      for (int q = 0; q < 4; ++q) {
        int off = (wbase[q] + (nf << 5)) ^ xmask[q];
        *(short*)((char*)m1w + off) = f2bf(silu_f(acc1A[nf][q] + b1v[nf]));
      }
    }
    #pragma unroll
    for (int kc = 0; kc < 4; ++kc)
      a2A[kc] = *(const short8*)((char*)m1w + rbase[kc]);
    #pragma unroll
    for (int nf = 0; nf < 8; ++nf) {
      #pragma unroll
      for (int q = 0; q < 4; ++q) {
        int off = (wbase[q] + (nf << 5)) ^ xmask[q];
        *(short*)((char*)m1w + off) = f2bf(silu_f(acc1B[nf][q] + b1v[nf]));
      }
    }
    #pragma unroll
    for (int kc = 0; kc < 4; ++kc)
      a2B[kc] = *(const short8*)((char*)m1w + rbase[kc]);

    f32x4 acc2A[8], acc2B[8];
    #pragma unroll
    for (int nf = 0; nf < 8; ++nf) { acc2A[nf] = zero4; acc2B[nf] = zero4; }
    __builtin_amdgcn_s_setprio(1);
    #pragma unroll
    for (int kc = 0; kc < 4; ++kc) {
      #pragma unroll
      for (int nf = 0; nf < 8; ++nf) {
        short8 bfv = F2[(kc*8 + nf)*64 + lane];
        acc2A[nf] = __builtin_amdgcn_mfma_f32_16x16x32_bf16(a2A[kc], bfv, acc2A[nf], 0,0,0);
        acc2B[nf] = __builtin_amdgcn_mfma_f32_16x16x32_bf16(a2B[kc], bfv, acc2B[nf], 0,0,0);
      }
    }
    __builtin_amdgcn_s_setprio(0);

    float dqA[4], dqB[4];
    #pragma unroll
    for (int q = 0; q < 4; ++q) {
      dqA[q] = __shfl(deA, hi*4 + q);   // lane s<16 holds edist[node*16+s]
      dqB[q] = __shfl(deB, hi*4 + q);
    }
    #pragma unroll
    for (int nf = 0; nf < 8; ++nf) {
      float sA = 0.f, sB = 0.f;
      #pragma unroll
      for (int q = 0; q < 4; ++q) {
        float mA = silu_f(acc2A[nf][q] + b2v[nf]);
        float mB = silu_f(acc2B[nf][q] + b2v[nf]);
        sA += (dqA[q] < 5.0f) ? mA : 0.f;
        sB += (dqB[q] < 5.0f) ? mB : 0.f;
      }
      sA += __shfl_xor(sA, 16); sA += __shfl_xor(sA, 32);
      sB += __shfl_xor(sB, 16); sB += __shfl_xor(sB, 32);
      if (hi == 0) {
        agg[(size_t)nA*HID + nf*16 + lo] = sA;
        agg[(size_t)nB*HID + nf*16 + lo] = sB;
      }
    }
  }
}

// ---------------------------------------------------------------------------
// Kernel 3: node MLP + residual + LayerNorm, agg==out in-place. (unchanged)
// ---------------------------------------------------------------------------
template<bool HBF>
__global__ __launch_bounds__(512)
void node_kernel(const float* __restrict__ h, const short* __restrict__ hb,
                 const float* agg,
                 const float* __restrict__ nw1, const float* __restrict__ nb1,
                 const float* __restrict__ nw2, const float* __restrict__ nb2,
                 const float* __restrict__ gam, const float* __restrict__ bet,
                 float* out)
{
  __shared__ __attribute__((aligned(16))) short8 G1[8*8*64];   // 65,536 B
  __shared__ __attribute__((aligned(16))) short8 G2[4*8*64];   // 32,768 B
  __shared__ __attribute__((aligned(16))) short m1s[8][2048];  // 32,768 B

  const int tid = threadIdx.x;
  for (int f = tid; f < 8*8*64; f += 512) {
    int kc = f >> 9, rem = f & 511, nf = rem >> 6, ln = rem & 63;
    int kb = kc*32 + (ln >> 4)*8, col = nf*16 + (ln & 15);
    short8 v;
    #pragma unroll
    for (int e = 0; e < 8; ++e) v[e] = f2bf(nw1[(kb + e)*128 + col]);
    G1[f] = v;
  }
  for (int f = tid; f < 4*8*64; f += 512) {
    int kc = f >> 9, rem = f & 511, nf = rem >> 6, ln = rem & 63;
    int kb = kc*32 + (ln >> 4)*8, col = nf*16 + (ln & 15);
    short8 v;
    #pragma unroll
    for (int e = 0; e < 8; ++e) v[e] = f2bf(nw2[(kb + e)*128 + col]);
    G2[f] = v;
  }
  __syncthreads();

  const int wv = tid >> 6, lane = tid & 63;
  const int lo = lane & 15, hi = lane >> 4;
  short* m1w = &m1s[wv][0];

  float b1v[8], b2v[8], gv[8], bv[8];
  #pragma unroll
  for (int nf = 0; nf < 8; ++nf) {
    b1v[nf] = nb1[nf*16 + lo];
    b2v[nf] = nb2[nf*16 + lo];
    gv[nf]  = gam[nf*16 + lo];
    bv[nf]  = bet[nf*16 + lo];
  }
  const f32x4 zero4 = {0.f, 0.f, 0.f, 0.f};

  const int row0 = (blockIdx.x * 8 + wv) * 16;

  const float* hrow = h   + (size_t)(row0 + lo) * HID;
  const float* arow = agg + (size_t)(row0 + lo) * HID;
  const short* hbrow = hb + (size_t)(row0 + lo) * HID;

  f32x4 acc1[8];
  #pragma unroll
  for (int nf = 0; nf < 8; ++nf) acc1[nf] = zero4;
  #pragma unroll
  for (int kc = 0; kc < 8; ++kc) {
    short8 a;
    if (kc < 4) {
      if constexpr (HBF) a = *(const short8*)(hbrow + kc*32 + hi*8);
      else               a = cv8(hrow + kc*32 + hi*8);
    } else {
      a = cv8(arow + (kc - 4)*32 + hi*8);
    }
    #pragma unroll
    for (int nf = 0; nf < 8; ++nf) {
      short8 bfv = G1[(kc*8 + nf)*64 + lane];
      acc1[nf] = __builtin_amdgcn_mfma_f32_16x16x32_bf16(a, bfv, acc1[nf], 0,0,0);
    }
  }

  #pragma unroll
  for (int nf = 0; nf < 8; ++nf) {
    #pragma unroll
    for (int q = 0; q < 4; ++q) {
      float s = silu_f(acc1[nf][q] + b1v[nf]);
      int row = hi*4 + q, col = nf*16 + lo;
      int byteoff = ((row << 8) + (col << 1)) ^ ((row & 7) << 4);
      *(short*)((char*)m1w + byteoff) = f2bf(s);
    }
  }

  f32x4 acc2[8];
  #pragma unroll
  for (int nf = 0; nf < 8; ++nf) acc2[nf] = zero4;
  #pragma unroll
  for (int kc = 0; kc < 4; ++kc) {
    int byteA = ((lo << 8) + ((kc*32 + hi*8) << 1)) ^ ((lo & 7) << 4);
    short8 a = *(const short8*)((char*)m1w + byteA);
    #pragma unroll
    for (int nf = 0; nf < 8; ++nf) {
      short8 bfv = G2[(kc*8 + nf)*64 + lane];
      acc2[nf] = __builtin_amdgcn_mfma_f32_16x16x32_bf16(a, bfv, acc2[nf], 0,0,0);
    }
  }

  float xv[4][8];
  #pragma unroll
  for (int nf = 0; nf < 8; ++nf) {
    #pragma unroll
    for (int q = 0; q < 4; ++q) {
      xv[q][nf] = acc2[nf][q] + b2v[nf]
                + h[(size_t)(row0 + hi*4 + q) * HID + nf*16 + lo];
    }
  }

  #pragma unroll
  for (int q = 0; q < 4; ++q) {
    float s = 0.0f;
    #pragma unroll
    for (int nf = 0; nf < 8; ++nf) s += xv[q][nf];
    s += __shfl_xor(s, 1); s += __shfl_xor(s, 2);
    s += __shfl_xor(s, 4); s += __shfl_xor(s, 8);
    float mu = s * 0.0078125f;
    float t = 0.0f;
    #pragma unroll
    for (int nf = 0; nf < 8; ++nf) { float d = xv[q][nf] - mu; t += d * d; }
    t += __shfl_xor(t, 1); t += __shfl_xor(t, 2);
    t += __shfl_xor(t, 4); t += __shfl_xor(t, 8);
    float inv = 1.0f / sqrtf(t * 0.0078125f + 1e-5f);
    #pragma unroll
    for (int nf = 0; nf < 8; ++nf) {
      float y = (xv[q][nf] - mu) * inv * gv[nf] + bv[nf];
      out[(size_t)(row0 + hi*4 + q) * HID + nf*16 + lo] = y;
    }
  }
}

// ---------------------------------------------------------------------------
extern "C" void kernel_launch(void* const* d_in, const int* in_sizes, int n_in,
                              void* d_out, int out_size, void* d_ws, size_t ws_size,
                              hipStream_t stream) {
  (void)in_sizes; (void)n_in; (void)out_size;
  const float* h   = (const float*)d_in[0];
  const float* pos = (const float*)d_in[1];
  const float* ew1 = (const float*)d_in[2];
  const float* eb1 = (const float*)d_in[3];
  const float* ew2 = (const float*)d_in[4];
  const float* eb2 = (const float*)d_in[5];
  const float* nw1 = (const float*)d_in[6];
  const float* nb1 = (const float*)d_in[7];
  const float* nw2 = (const float*)d_in[8];
  const float* nb2 = (const float*)d_in[9];
  const float* gam = (const float*)d_in[10];
  const float* bet = (const float*)d_in[11];

  // ws: eidx 2MB | edist 2MB | hb(bf16 h) 8.4MB (optional). agg lives in d_out.
  const size_t base_need = (size_t)NBATCH * NNODE * KNN * 8;                 // 4 MB
  const size_t hbf_need  = base_need + (size_t)NBATCH * NNODE * HID * 2;     // +8.4 MB
  if (ws_size < base_need) return;
  const bool use_hbf = (ws_size >= hbf_need);

  char* wsp = (char*)d_ws;
  int*   eidx  = (int*)wsp;
  float* edist = (float*)(wsp + (size_t)NBATCH * NNODE * KNN * 4);
  short* hb    = (short*)(wsp + base_need);
  float* agg   = (float*)d_out;

  if (use_hbf) {
    hcvt_kernel<<<dim3(2048), dim3(256), 0, stream>>>(h, hb);
  }
  knn_kernel<<<dim3(1024), dim3(512), 0, stream>>>(pos, eidx, edist);
  if (use_hbf) {
    edge_kernel<true ><<<dim3(256), dim3(512), 0, stream>>>(h, hb, eidx, edist,
                                                            ew1, eb1, ew2, eb2, agg);
    node_kernel<true ><<<dim3(256), dim3(512), 0, stream>>>(h, hb, agg, nw1, nb1,
                                                            nw2, nb2, gam, bet, (float*)d_out);
  } else {
    edge_kernel<false><<<dim3(256), dim3(512), 0, stream>>>(h, hb, eidx, edist,
                                                            ew1, eb1, ew2, eb2, agg);
    node_kernel<false><<<dim3(256), dim3(512), 0, stream>>>(h, hb, agg, nw1, nb1,
                                                            nw2, nb2, gam, bet, (float*)d_out);
  }
}